// Round 18
// baseline (214.346 us; speedup 1.0000x reference)
//
#include <hip/hip_runtime.h>

#define L_LEN 262144
#define KSZ 257
#define BLK 256
#define TILE 4096             // outputs per conv block
#define HALO (KSZ - 1)
#define NBIN 4096             // top-12-bit histogram bins
#define SEGCAP 256            // candidate cap per (sample,chunk) segment
#define NCHUNK 32             // chunks per sample in write/gather
#define CHUNK (L_LEN / NCHUNK)   // 8192
#define CWIN (CHUNK + HALO)      // 8448 staged x floats
#define CANDMAX 6144          // per-sample candidate list cap (LDS, 2 bins)
#define TIECAP 1024

#define LDSW 4368             // mfma: staged x window (bf16 hi only)
#define NJ2 18                // mfma 32x32x16: j0 = 16*f, f = 0..17

typedef __attribute__((ext_vector_type(8))) short bf16x8;
typedef __attribute__((ext_vector_type(16))) float f32x16;

__device__ __forceinline__ ushort bf16_rne(float f) {
    const unsigned u = __float_as_uint(f);
    return (ushort)((u + 0x7FFFu + ((u >> 16) & 1u)) >> 16);
}

// ---------- Kernel Z: fast workspace zero (ghist 1MB + delta 256B) -----------
__global__ __launch_bounds__(BLK) void zero_ws_kernel(uint4* __restrict__ p, int n16) {
    const int i = blockIdx.x * BLK + threadIdx.x;
    if (i < n16) p[i] = make_uint4(0u, 0u, 0u, 0u);
}

// ---------- Kernel A: 32x32x16 2-product split-bf16 MFMA conv ----------------
// O[m] = sum_j w[j] * x[m-128+j], m = tstart + wv*1024 + 32*i + c.
// Block f covers taps u = 16f + k (k in [0,16)); u bijects onto [0,288) so
// each tap accumulates once: O = sum_u x[win + 32i + u] * w[u - c] (w 0-pad).
// A[i][k] = xh[wvbase + 16f + 32i + k]  (i = lane&31, k = 8*(lane>>5)+e)
// B[k][c] = wpad[16f + k - c]           (c = lane&31)
// D: col = lane&31, row = (r&3) + 8*(r>>2) + 4*(lane>>5)   [m74/m101 verified]
// Error ~5e-3 (x_lo dropped): fine for 12-bit binning; 3-bin boundary band is
// refined exactly in the fused write/gather kernel, so selection stays exact.
template<bool HIST>
__global__ __launch_bounds__(BLK) void mfma_conv_kernel(const float* __restrict__ in,
                                                        const float* __restrict__ w,
                                                        float* __restrict__ out,
                                                        unsigned* __restrict__ ghist) {
    __shared__ ushort xh[LDSW];
    __shared__ unsigned shist[HIST ? NBIN : 1];

    const int t = threadIdx.x;
    const int sample = blockIdx.x >> 6;      // 64 tiles per row
    const int tile   = blockIdx.x & 63;
    const float* xrow = in  + (size_t)sample * L_LEN;
    float*       orow = out + (size_t)sample * L_LEN;
    const int tstart = tile * TILE;
    const int gbase  = tstart - (KSZ / 2);   // -128

    if (HIST) for (int h = t; h < NBIN; h += BLK) shist[h] = 0u;

    // stage x window as bf16 (hi only)
    for (int i4 = t; i4 < LDSW / 4; i4 += BLK) {
        const int g = gbase + i4 * 4;
        float4 v;
        if ((unsigned)g <= (unsigned)(L_LEN - 4)) v = *(const float4*)(xrow + g);
        else v = make_float4(0.f, 0.f, 0.f, 0.f);
        *(ushort4*)(&xh[i4 * 4]) = make_ushort4(bf16_rne(v.x), bf16_rne(v.y),
                                                bf16_rne(v.z), bf16_rne(v.w));
    }

    // weight B-fragments (hi + lo) in registers
    const int lane = t & 63;
    const int cc = lane & 31;                // A row i / B,D col c
    const int hb = lane >> 5;                // k half: k = 8*hb + e
    bf16x8 Bh[NJ2], Bl[NJ2];
#pragma unroll
    for (int f = 0; f < NJ2; ++f) {
#pragma unroll
        for (int e = 0; e < 8; ++e) {
            const int j = f * 16 + 8 * hb + e - cc;
            const float v = ((unsigned)j <= 256u) ? w[j] : 0.f;
            const ushort h = bf16_rne(v);
            Bh[f][e] = (short)h;
            Bl[f][e] = (short)bf16_rne(v - __uint_as_float((unsigned)h << 16));
        }
    }
    __syncthreads();

    const int wv = t >> 6;                   // wave id: owns 1024 outputs
    const int wvbase = wv * 1024;
    const int arow = 32 * cc + 8 * hb;       // multiple of 8 -> 16B aligned

    f32x16 acc = {};
#pragma unroll
    for (int f = 0; f < NJ2; ++f) {
        const bf16x8 Ah = *(const bf16x8*)(&xh[wvbase + f * 16 + arow]);
        acc = __builtin_amdgcn_mfma_f32_32x32x16_bf16(Ah, Bh[f], acc, 0, 0, 0);
        acc = __builtin_amdgcn_mfma_f32_32x32x16_bf16(Ah, Bl[f], acc, 0, 0, 0);
    }

#pragma unroll
    for (int r = 0; r < 16; ++r) {
        const int row = (r & 3) + 8 * (r >> 2) + 4 * hb;
        const float v = acc[r];
        orow[tstart + wvbase + 32 * row + cc] = v;
        if (HIST) {
            const unsigned u = (__float_as_uint(v) & 0x7fffffffu) >> 19;
            atomicAdd(&shist[u], 1u);
        }
    }

    if (HIST) {
        __syncthreads();
        for (int h = t; h < NBIN; h += BLK) {
            const unsigned c = shist[h];
            if (c) atomicAdd(&ghist[(size_t)sample * NBIN + h], c);
        }
    }
}

// ---------- Kernel B: per-sample bin selection from histogram ----------------
__global__ __launch_bounds__(1024) void bin_select_kernel(const unsigned* __restrict__ ghist,
                                                          int2* __restrict__ sel,
                                                          const int* __restrict__ kptr) {
    __shared__ int ss[1024];
    const int t = threadIdx.x;
    const int b = blockIdx.x;
    const unsigned* hist = ghist + (size_t)b * NBIN;
    const int k = kptr[0];

    const int g4 = t * 4;
    const int h0 = (int)hist[g4], h1 = (int)hist[g4 + 1],
              h2 = (int)hist[g4 + 2], h3 = (int)hist[g4 + 3];
    ss[t] = h0 + h1 + h2 + h3;
    __syncthreads();
    for (int off = 1; off < 1024; off <<= 1) {
        const int add = (t + off < 1024) ? ss[t + off] : 0;
        __syncthreads();
        ss[t] += add;
        __syncthreads();
    }
    const int S0 = ss[t];
    const int S4 = (t < 1023) ? ss[t + 1] : 0;
    const int S1 = S0 - h0, S2 = S1 - h1, S3 = S2 - h2;
    if (S0 >= k && S1 < k) sel[b] = make_int2(g4,     k - S1);
    if (S1 >= k && S2 < k) sel[b] = make_int2(g4 + 1, k - S2);
    if (S2 >= k && S3 < k) sel[b] = make_int2(g4 + 2, k - S3);
    if (S3 >= k && S4 < k) sel[b] = make_int2(g4 + 3, k - S4);
}

// ---------- Kernel C: FUSED write extrema + exact band refine + gather -------
__global__ __launch_bounds__(BLK) void write_gather_kernel(const float* __restrict__ x,
                                                           const float* __restrict__ w,
                                                           const float* __restrict__ sim,
                                                           float* __restrict__ ext,
                                                           uint2* __restrict__ cand,
                                                           int* __restrict__ segCnt,
                                                           const int2* __restrict__ sel,
                                                           int* __restrict__ delta) {
    __shared__ float lx[CWIN + CWIN / 16];   // padded: elem e -> lx[e + e/16]
    __shared__ float lw[KSZ];
    __shared__ ushort wl[CHUNK];             // local idx (13b) | pre_gt<<15
    __shared__ int s_cnt, s_wcnt, s_delta;
    const int t = threadIdx.x;
    const int b = blockIdx.x >> 5;
    const int chunk = blockIdx.x & (NCHUNK - 1);
    const unsigned selBin = (unsigned)sel[b].x;
    const float* xrow = x   + (size_t)b * L_LEN;
    const float* row  = sim + (size_t)b * L_LEN;
    float*       erow = ext + (size_t)b * L_LEN;
    uint2* seg = cand + ((size_t)b * NCHUNK + chunk) * SEGCAP;
    const int base = chunk * CHUNK;
    const int gbase = base - (KSZ / 2);      // aligned mod 4

    if (t == 0) { s_cnt = 0; s_wcnt = 0; s_delta = 0; }
    for (int i = t; i < KSZ; i += BLK) lw[i] = w[i];

    for (int i4 = t; i4 < CWIN / 4; i4 += BLK) {
        const int g = gbase + i4 * 4;
        float4 v;
        if ((unsigned)g <= (unsigned)(L_LEN - 4)) v = *(const float4*)(xrow + g);
        else v = make_float4(0.f, 0.f, 0.f, 0.f);
        const int ib = i4 * 4;
        const int p = ib + (ib >> 4);
        lx[p] = v.x; lx[p + 1] = v.y; lx[p + 2] = v.z; lx[p + 3] = v.w;
    }
    __syncthreads();

    // stream sim: final ext for non-band; worklist for band (placeholder 0)
    for (int i = t; i < CHUNK / 4; i += BLK) {
        const int g = base + i * 4;
        const float4 v = *(const float4*)(row + g);
        const float vv[4] = {v.x, v.y, v.z, v.w};
        float o[4];
#pragma unroll
        for (int e = 0; e < 4; ++e) {
            const unsigned u12 = (__float_as_uint(vv[e]) & 0x7fffffffu) >> 19;
            if ((unsigned)(u12 + 1u - selBin) <= 2u) {   // band: defer
                o[e] = 0.f;
                const int p = atomicAdd(&s_wcnt, 1);
                wl[p] = (ushort)((i * 4 + e) | ((int)(u12 > selBin) << 15));
            } else {
                o[e] = (u12 > selBin) ? vv[e] : 0.f;
            }
        }
        *(float4*)(erow + g) = make_float4(o[0], o[1], o[2], o[3]);
    }
    __syncthreads();

    // process band: one thread per element, exact serial fma chain from LDS
    const int wc = s_wcnt;
    for (int p = t; p < wc; p += BLK) {
        const ushort rec = wl[p];
        const int li = rec & 0x1FFF;                     // local sim idx
        const int pre_gt = (rec >> 15) & 1;
        float acc = 0.f;
        for (int j = 0; j < KSZ; ++j) {                  // EXACT ascending-j chain
            const int el = li + j;
            acc = fmaf(lw[j], lx[el + (el >> 4)], acc);
        }
        const unsigned u = __float_as_uint(acc) & 0x7fffffffu;
        const unsigned u12 = u >> 19;
        const int post_gt = (u12 > selBin) ? 1 : 0;
        if (post_gt != pre_gt) atomicAdd(&s_delta, post_gt - pre_gt);
        if (post_gt) erow[base + li] = acc;              // else stays 0
        if ((unsigned)(selBin - u12) <= 1u) {            // {selBin-1, selBin}
            const int p2 = atomicAdd(&s_cnt, 1);
            if (p2 < SEGCAP) seg[p2] = make_uint2(u, (unsigned)(base + li));
        }
    }
    __syncthreads();
    if (t == 0) {
        segCnt[b * NCHUNK + chunk] = (s_cnt < SEGCAP) ? s_cnt : SEGCAP;
        if (s_delta != 0) atomicAdd(&delta[b], s_delta);
    }
}

// ---------- Kernel D: exact finalize (20-bit relative radix over 2 bins) -----
__global__ __launch_bounds__(1024) void finalize_kernel(const float* __restrict__ sim,
                                                        float* __restrict__ ext,
                                                        const uint2* __restrict__ cand,
                                                        const int* __restrict__ segCnt,
                                                        const int2* __restrict__ sel,
                                                        const int* __restrict__ delta) {
    __shared__ int hist[1024];
    __shared__ int ss[1024];
    __shared__ uint2 list[CANDMAX];          // 48 KB
    __shared__ int tie[TIECAP];
    __shared__ int scnt[NCHUNK];
    __shared__ int segoff[NCHUNK + 1];
    __shared__ int s_b1, s_kk2, s_Tlow, s_m, s_tieCnt;
    const int t = threadIdx.x;
    const int b = blockIdx.x;
    const float* srow = sim + (size_t)b * L_LEN;
    float*       erow = ext + (size_t)b * L_LEN;
    const unsigned selBin = (unsigned)sel[b].x;
    const unsigned vbase = (selBin > 0 ? selBin - 1 : 0) << 19;
    int kk = sel[b].y - delta[b];            // exact count to take in-bin

    if (t < NCHUNK) scnt[t] = segCnt[b * NCHUNK + t];
    __syncthreads();
    if (t == 0) {
        int a = 0;
        for (int s = 0; s < NCHUNK; ++s) { segoff[s] = a; a += scnt[s]; }
        segoff[NCHUNK] = a;
    }
    if (t == 1) s_tieCnt = 0;
    __syncthreads();
    int cnt = segoff[NCHUNK]; if (cnt > CANDMAX) cnt = CANDMAX;
    if (kk <= 0) return;                     // degenerate: nothing taken in-bin
    if (kk > cnt) kk = cnt;

    for (int j = t; j < NCHUNK * SEGCAP; j += 1024) {
        const int s = j >> 8;                // SEGCAP == 256
        const int i = j & (SEGCAP - 1);
        if (i < scnt[s]) {
            const int dst = segoff[s] + i;
            if (dst < CANDMAX)
                list[dst] = cand[((size_t)b * NCHUNK + s) * SEGCAP + i];
        }
    }
    __syncthreads();

    // round 1: vrel bits 19..10
    hist[t] = 0;
    __syncthreads();
    for (int p = t; p < cnt; p += 1024)
        atomicAdd(&hist[(list[p].x - vbase) >> 10], 1);
    __syncthreads();
    ss[t] = hist[t];
    __syncthreads();
    for (int off = 1; off < 1024; off <<= 1) {
        const int add = (t + off < 1024) ? ss[t + off] : 0;
        __syncthreads();
        ss[t] += add;
        __syncthreads();
    }
    {
        const int S = ss[t];
        const int Sn = (t < 1023) ? ss[t + 1] : 0;
        if (S >= kk && Sn < kk) { s_b1 = t; s_kk2 = kk - Sn; }
    }
    __syncthreads();
    const int b1 = s_b1, kk2 = s_kk2;

    // round 2: vrel bits 9..0
    hist[t] = 0;
    __syncthreads();
    for (int p = t; p < cnt; p += 1024) {
        const unsigned v = list[p].x - vbase;
        if ((int)(v >> 10) == b1) atomicAdd(&hist[v & 1023u], 1);
    }
    __syncthreads();
    ss[t] = hist[t];
    __syncthreads();
    for (int off = 1; off < 1024; off <<= 1) {
        const int add = (t + off < 1024) ? ss[t + off] : 0;
        __syncthreads();
        ss[t] += add;
        __syncthreads();
    }
    {
        const int S = ss[t];
        const int Sn = (t < 1023) ? ss[t + 1] : 0;
        if (S >= kk2 && Sn < kk2) { s_Tlow = (b1 << 10) | t; s_m = kk2 - Sn; }
    }
    __syncthreads();
    const unsigned Tlow = (unsigned)s_Tlow;
    const int m = s_m;

    for (int p = t; p < cnt; p += 1024) {
        const unsigned v = list[p].x - vbase;
        const int idx = (int)list[p].y;
        if (v > Tlow) erow[idx] = srow[idx];
        else if (v == Tlow) {
            const int q = atomicAdd(&s_tieCnt, 1);
            if (q < TIECAP) tie[q] = idx;
        }
    }
    __syncthreads();
    int tc = s_tieCnt; if (tc > TIECAP) tc = TIECAP;
    for (int p = t; p < tc; p += 1024) {
        const int idx = tie[p];
        int rank = 0;
        for (int q = 0; q < tc; ++q) rank += (tie[q] < idx) ? 1 : 0;
        if (rank < m) erow[idx] = srow[idx];
    }
}

// ----------------------------------------------------------------------------
extern "C" void kernel_launch(void* const* d_in, const int* in_sizes, int n_in,
                              void* d_out, int out_size, void* d_ws, size_t ws_size,
                              hipStream_t stream) {
    const float* x    = (const float*)d_in[0];
    const float* w    = (const float*)d_in[1];
    const int*   kptr = (const int*)d_in[2];
    float* out = (float*)d_out;

    const int total = in_sizes[0];            // B * L
    const int B = total / L_LEN;              // 64

    float* recon = out;
    float* sim   = out + (size_t)total;
    float* ext   = out + 2 * (size_t)total;

    // workspace layout
    uint8_t* ws = (uint8_t*)d_ws;
    unsigned* ghist  = (unsigned*)ws;                         // 1 MB
    int*      delta  = (int*)(ws + 1048576);                  // 256 B
    int2*     sel    = (int2*)(ws + 1048576 + 1024);          // 512 B
    int*      segCnt = (int*)(ws + 1048576 + 2048);           // 8 KB
    uint2*    cand   = (uint2*)(ws + 1048576 + 2048 + 8192);  // 4 MB

    // zero ghist + delta
    const int n16 = (1048576 + 1024) / 16;
    zero_ws_kernel<<<dim3((n16 + BLK - 1) / BLK), BLK, 0, stream>>>((uint4*)ws, n16);

    mfma_conv_kernel<true><<<dim3(B * 64), BLK, 0, stream>>>(x, w, sim, ghist);
    bin_select_kernel<<<dim3(B), 1024, 0, stream>>>(ghist, sel, kptr);
    write_gather_kernel<<<dim3(B * NCHUNK), BLK, 0, stream>>>(x, w, sim, ext, cand, segCnt, sel, delta);
    finalize_kernel<<<dim3(B), 1024, 0, stream>>>(sim, ext, cand, segCnt, sel, delta);
    mfma_conv_kernel<false><<<dim3(B * 64), BLK, 0, stream>>>(ext, w, recon, nullptr);
}

// Round 19
// 155.263 us; speedup vs baseline: 1.3805x; 1.3805x over previous
//
#include <hip/hip_runtime.h>

#define L_LEN 262144
#define KSZ 257
#define BLK 256
#define TILE 4096             // outputs per conv block
#define HALO (KSZ - 1)
#define NBIN 4096             // top-12-bit histogram bins
#define SEGCAP 256            // candidate cap per (sample,chunk) segment
#define NCHUNK 32             // chunks per sample in write/gather
#define CHUNK (L_LEN / NCHUNK)   // 8192
#define CWIN (CHUNK + HALO)      // 8448 staged x floats
#define CANDMAX 6144          // per-sample candidate list cap (LDS, 2 bins)
#define TIECAP 1024

#define LDSW 4368             // mfma: staged x window (bf16 hi only)
#define NJ 9                  // mfma: j0 blocks 0,32,...,256

typedef __attribute__((ext_vector_type(8))) short bf16x8;
typedef __attribute__((ext_vector_type(4))) float f32x4;

__device__ __forceinline__ ushort bf16_rne(float f) {
    const unsigned u = __float_as_uint(f);
    return (ushort)((u + 0x7FFFu + ((u >> 16) & 1u)) >> 16);
}

// ---------- Kernel Z: fast workspace zero (ghist 1MB + delta 256B) -----------
__global__ __launch_bounds__(BLK) void zero_ws_kernel(uint4* __restrict__ p, int n16) {
    const int i = blockIdx.x * BLK + threadIdx.x;
    if (i < n16) p[i] = make_uint4(0u, 0u, 0u, 0u);
}

// ---------- Kernel A: 2-product split-bf16 MFMA conv (+ optional histogram) --
// O[m] = sum_j w[j] * x[m-128+j].  D[i][c] = O[mb + 16*i + c].
// A[i][k] = x_hi[...]; B = w_hi / w_lo Toeplitz fragments. Error ~5e-3:
// fine for 12-bit binning; the 3-bin boundary band is refined exactly in the
// fused write/gather kernel, so selection stays exact.
// NOTE (r18): do NOT switch to 32x32x16 — B-frags double to 144 VGPRs and
// occupancy collapses (155 -> 214 us measured).
template<bool HIST>
__global__ __launch_bounds__(BLK) void mfma_conv_kernel(const float* __restrict__ in,
                                                        const float* __restrict__ w,
                                                        float* __restrict__ out,
                                                        unsigned* __restrict__ ghist) {
    __shared__ ushort xh[LDSW];
    __shared__ unsigned shist[HIST ? NBIN : 1];

    const int t = threadIdx.x;
    const int sample = blockIdx.x >> 6;      // 64 tiles per row
    const int tile   = blockIdx.x & 63;
    const float* xrow = in  + (size_t)sample * L_LEN;
    float*       orow = out + (size_t)sample * L_LEN;
    const int tstart = tile * TILE;
    const int gbase  = tstart - (KSZ / 2);   // -128

    if (HIST) for (int h = t; h < NBIN; h += BLK) shist[h] = 0u;

    for (int i4 = t; i4 < LDSW / 4; i4 += BLK) {
        const int g = gbase + i4 * 4;
        float4 v;
        if ((unsigned)g <= (unsigned)(L_LEN - 4)) v = *(const float4*)(xrow + g);
        else v = make_float4(0.f, 0.f, 0.f, 0.f);
        *(ushort4*)(&xh[i4 * 4]) = make_ushort4(bf16_rne(v.x), bf16_rne(v.y),
                                                bf16_rne(v.z), bf16_rne(v.w));
    }

    const int lane = t & 63;
    const int cc = lane & 15;
    const int bb = lane >> 4;
    bf16x8 Bh[NJ], Bl[NJ];
#pragma unroll
    for (int f = 0; f < NJ; ++f) {
#pragma unroll
        for (int e = 0; e < 8; ++e) {
            const int j = f * 32 + 8 * bb + e - cc;
            const float v = ((unsigned)j <= 256u) ? w[j] : 0.f;
            const ushort h = bf16_rne(v);
            Bh[f][e] = (short)h;
            Bl[f][e] = (short)bf16_rne(v - __uint_as_float((unsigned)h << 16));
        }
    }
    __syncthreads();

    const int wv = t >> 6;
    const int wvbase = wv * 1024;
    const int arow = 16 * cc + 8 * bb;

    f32x4 acc[4] = {};
#pragma unroll
    for (int f = 0; f < NJ; ++f) {
#pragma unroll
        for (int st = 0; st < 4; ++st) {
            const int ao = wvbase + st * 256 + f * 32 + arow;
            const bf16x8 Ah = *(const bf16x8*)(&xh[ao]);
            acc[st] = __builtin_amdgcn_mfma_f32_16x16x32_bf16(Ah, Bh[f], acc[st], 0, 0, 0);
            acc[st] = __builtin_amdgcn_mfma_f32_16x16x32_bf16(Ah, Bl[f], acc[st], 0, 0, 0);
        }
    }

#pragma unroll
    for (int st = 0; st < 4; ++st) {
        const int mbase = tstart + wvbase + st * 256 + 64 * bb + cc;
#pragma unroll
        for (int r = 0; r < 4; ++r) {
            const float v = acc[st][r];
            orow[mbase + 16 * r] = v;
            if (HIST) {
                const unsigned u = (__float_as_uint(v) & 0x7fffffffu) >> 19;
                atomicAdd(&shist[u], 1u);
            }
        }
    }

    if (HIST) {
        __syncthreads();
        for (int h = t; h < NBIN; h += BLK) {
            const unsigned c = shist[h];
            if (c) atomicAdd(&ghist[(size_t)sample * NBIN + h], c);
        }
    }
}

// ---------- Kernel B: per-sample bin selection from histogram ----------------
__global__ __launch_bounds__(1024) void bin_select_kernel(const unsigned* __restrict__ ghist,
                                                          int2* __restrict__ sel,
                                                          const int* __restrict__ kptr) {
    __shared__ int ss[1024];
    const int t = threadIdx.x;
    const int b = blockIdx.x;
    const unsigned* hist = ghist + (size_t)b * NBIN;
    const int k = kptr[0];

    const int g4 = t * 4;
    const int h0 = (int)hist[g4], h1 = (int)hist[g4 + 1],
              h2 = (int)hist[g4 + 2], h3 = (int)hist[g4 + 3];
    ss[t] = h0 + h1 + h2 + h3;
    __syncthreads();
    for (int off = 1; off < 1024; off <<= 1) {
        const int add = (t + off < 1024) ? ss[t + off] : 0;
        __syncthreads();
        ss[t] += add;
        __syncthreads();
    }
    const int S0 = ss[t];
    const int S4 = (t < 1023) ? ss[t + 1] : 0;
    const int S1 = S0 - h0, S2 = S1 - h1, S3 = S2 - h2;
    if (S0 >= k && S1 < k) sel[b] = make_int2(g4,     k - S1);
    if (S1 >= k && S2 < k) sel[b] = make_int2(g4 + 1, k - S2);
    if (S2 >= k && S3 < k) sel[b] = make_int2(g4 + 2, k - S3);
    if (S3 >= k && S4 < k) sel[b] = make_int2(g4 + 3, k - S4);
}

// ---------- Kernel C: FUSED write extrema + exact band refine + gather -------
// Stages the chunk's x window (36KB) in LDS. Streams sim: non-band elements
// get final ext immediately (5e-3 error can't cross a full bin). Band elements
// {selBin-1, selBin, selBin+1} go to a ushort worklist (cap = CHUNK: cannot
// overflow), then ONE thread each recomputes the EXACT ascending-j fp32 fma
// chain from LDS (bit-identical to the proven conv), decides keep/candidate,
// and accumulates the count(>selBin) delta.
__global__ __launch_bounds__(BLK) void write_gather_kernel(const float* __restrict__ x,
                                                           const float* __restrict__ w,
                                                           const float* __restrict__ sim,
                                                           float* __restrict__ ext,
                                                           uint2* __restrict__ cand,
                                                           int* __restrict__ segCnt,
                                                           const int2* __restrict__ sel,
                                                           int* __restrict__ delta) {
    __shared__ float lx[CWIN + CWIN / 16];   // padded: elem e -> lx[e + e/16]
    __shared__ float lw[KSZ];
    __shared__ ushort wl[CHUNK];             // local idx (13b) | pre_gt<<15
    __shared__ int s_cnt, s_wcnt, s_delta;
    const int t = threadIdx.x;
    const int b = blockIdx.x >> 5;
    const int chunk = blockIdx.x & (NCHUNK - 1);
    const unsigned selBin = (unsigned)sel[b].x;
    const float* xrow = x   + (size_t)b * L_LEN;
    const float* row  = sim + (size_t)b * L_LEN;
    float*       erow = ext + (size_t)b * L_LEN;
    uint2* seg = cand + ((size_t)b * NCHUNK + chunk) * SEGCAP;
    const int base = chunk * CHUNK;
    const int gbase = base - (KSZ / 2);      // aligned mod 4

    if (t == 0) { s_cnt = 0; s_wcnt = 0; s_delta = 0; }
    for (int i = t; i < KSZ; i += BLK) lw[i] = w[i];

    // stage x window (zero-padded), +1-per-16 padding
    for (int i4 = t; i4 < CWIN / 4; i4 += BLK) {
        const int g = gbase + i4 * 4;
        float4 v;
        if ((unsigned)g <= (unsigned)(L_LEN - 4)) v = *(const float4*)(xrow + g);
        else v = make_float4(0.f, 0.f, 0.f, 0.f);
        const int ib = i4 * 4;
        const int p = ib + (ib >> 4);
        lx[p] = v.x; lx[p + 1] = v.y; lx[p + 2] = v.z; lx[p + 3] = v.w;
    }
    __syncthreads();

    // stream sim: final ext for non-band; worklist for band (placeholder 0)
    for (int i = t; i < CHUNK / 4; i += BLK) {
        const int g = base + i * 4;
        const float4 v = *(const float4*)(row + g);
        const float vv[4] = {v.x, v.y, v.z, v.w};
        float o[4];
#pragma unroll
        for (int e = 0; e < 4; ++e) {
            const unsigned u12 = (__float_as_uint(vv[e]) & 0x7fffffffu) >> 19;
            if ((unsigned)(u12 + 1u - selBin) <= 2u) {   // band: defer
                o[e] = 0.f;
                const int p = atomicAdd(&s_wcnt, 1);
                wl[p] = (ushort)((i * 4 + e) | ((int)(u12 > selBin) << 15));
            } else {
                o[e] = (u12 > selBin) ? vv[e] : 0.f;
            }
        }
        *(float4*)(erow + g) = make_float4(o[0], o[1], o[2], o[3]);
    }
    __syncthreads();

    // process band: one thread per element, exact serial fma chain from LDS
    const int wc = s_wcnt;
    for (int p = t; p < wc; p += BLK) {
        const ushort rec = wl[p];
        const int li = rec & 0x1FFF;                     // local sim idx
        const int pre_gt = (rec >> 15) & 1;
        float acc = 0.f;
        for (int j = 0; j < KSZ; ++j) {                  // EXACT ascending-j chain
            const int el = li + j;
            acc = fmaf(lw[j], lx[el + (el >> 4)], acc);
        }
        const unsigned u = __float_as_uint(acc) & 0x7fffffffu;
        const unsigned u12 = u >> 19;
        const int post_gt = (u12 > selBin) ? 1 : 0;
        if (post_gt != pre_gt) atomicAdd(&s_delta, post_gt - pre_gt);
        if (post_gt) erow[base + li] = acc;              // else stays 0
        if ((unsigned)(selBin - u12) <= 1u) {            // {selBin-1, selBin}
            const int p2 = atomicAdd(&s_cnt, 1);
            if (p2 < SEGCAP) seg[p2] = make_uint2(u, (unsigned)(base + li));
        }
    }
    __syncthreads();
    if (t == 0) {
        segCnt[b * NCHUNK + chunk] = (s_cnt < SEGCAP) ? s_cnt : SEGCAP;
        if (s_delta != 0) atomicAdd(&delta[b], s_delta);
    }
}

// ---------- Kernel D: exact finalize (20-bit relative radix over 2 bins) -----
__global__ __launch_bounds__(1024) void finalize_kernel(const float* __restrict__ sim,
                                                        float* __restrict__ ext,
                                                        const uint2* __restrict__ cand,
                                                        const int* __restrict__ segCnt,
                                                        const int2* __restrict__ sel,
                                                        const int* __restrict__ delta) {
    __shared__ int hist[1024];
    __shared__ int ss[1024];
    __shared__ uint2 list[CANDMAX];          // 48 KB
    __shared__ int tie[TIECAP];
    __shared__ int scnt[NCHUNK];
    __shared__ int segoff[NCHUNK + 1];
    __shared__ int s_b1, s_kk2, s_Tlow, s_m, s_tieCnt;
    const int t = threadIdx.x;
    const int b = blockIdx.x;
    const float* srow = sim + (size_t)b * L_LEN;
    float*       erow = ext + (size_t)b * L_LEN;
    const unsigned selBin = (unsigned)sel[b].x;
    const unsigned vbase = (selBin > 0 ? selBin - 1 : 0) << 19;
    int kk = sel[b].y - delta[b];            // exact count to take in-bin

    if (t < NCHUNK) scnt[t] = segCnt[b * NCHUNK + t];
    __syncthreads();
    if (t == 0) {
        int a = 0;
        for (int s = 0; s < NCHUNK; ++s) { segoff[s] = a; a += scnt[s]; }
        segoff[NCHUNK] = a;
    }
    if (t == 1) s_tieCnt = 0;
    __syncthreads();
    int cnt = segoff[NCHUNK]; if (cnt > CANDMAX) cnt = CANDMAX;
    if (kk <= 0) return;                     // degenerate: nothing taken in-bin
    if (kk > cnt) kk = cnt;

    for (int j = t; j < NCHUNK * SEGCAP; j += 1024) {
        const int s = j >> 8;                // SEGCAP == 256
        const int i = j & (SEGCAP - 1);
        if (i < scnt[s]) {
            const int dst = segoff[s] + i;
            if (dst < CANDMAX)
                list[dst] = cand[((size_t)b * NCHUNK + s) * SEGCAP + i];
        }
    }
    __syncthreads();

    // round 1: vrel bits 19..10
    hist[t] = 0;
    __syncthreads();
    for (int p = t; p < cnt; p += 1024)
        atomicAdd(&hist[(list[p].x - vbase) >> 10], 1);
    __syncthreads();
    ss[t] = hist[t];
    __syncthreads();
    for (int off = 1; off < 1024; off <<= 1) {
        const int add = (t + off < 1024) ? ss[t + off] : 0;
        __syncthreads();
        ss[t] += add;
        __syncthreads();
    }
    {
        const int S = ss[t];
        const int Sn = (t < 1023) ? ss[t + 1] : 0;
        if (S >= kk && Sn < kk) { s_b1 = t; s_kk2 = kk - Sn; }
    }
    __syncthreads();
    const int b1 = s_b1, kk2 = s_kk2;

    // round 2: vrel bits 9..0
    hist[t] = 0;
    __syncthreads();
    for (int p = t; p < cnt; p += 1024) {
        const unsigned v = list[p].x - vbase;
        if ((int)(v >> 10) == b1) atomicAdd(&hist[v & 1023u], 1);
    }
    __syncthreads();
    ss[t] = hist[t];
    __syncthreads();
    for (int off = 1; off < 1024; off <<= 1) {
        const int add = (t + off < 1024) ? ss[t + off] : 0;
        __syncthreads();
        ss[t] += add;
        __syncthreads();
    }
    {
        const int S = ss[t];
        const int Sn = (t < 1023) ? ss[t + 1] : 0;
        if (S >= kk2 && Sn < kk2) { s_Tlow = (b1 << 10) | t; s_m = kk2 - Sn; }
    }
    __syncthreads();
    const unsigned Tlow = (unsigned)s_Tlow;
    const int m = s_m;

    for (int p = t; p < cnt; p += 1024) {
        const unsigned v = list[p].x - vbase;
        const int idx = (int)list[p].y;
        if (v > Tlow) erow[idx] = srow[idx];
        else if (v == Tlow) {
            const int q = atomicAdd(&s_tieCnt, 1);
            if (q < TIECAP) tie[q] = idx;
        }
    }
    __syncthreads();
    int tc = s_tieCnt; if (tc > TIECAP) tc = TIECAP;
    for (int p = t; p < tc; p += 1024) {
        const int idx = tie[p];
        int rank = 0;
        for (int q = 0; q < tc; ++q) rank += (tie[q] < idx) ? 1 : 0;
        if (rank < m) erow[idx] = srow[idx];
    }
}

// ----------------------------------------------------------------------------
extern "C" void kernel_launch(void* const* d_in, const int* in_sizes, int n_in,
                              void* d_out, int out_size, void* d_ws, size_t ws_size,
                              hipStream_t stream) {
    const float* x    = (const float*)d_in[0];
    const float* w    = (const float*)d_in[1];
    const int*   kptr = (const int*)d_in[2];
    float* out = (float*)d_out;

    const int total = in_sizes[0];            // B * L
    const int B = total / L_LEN;              // 64

    float* recon = out;
    float* sim   = out + (size_t)total;
    float* ext   = out + 2 * (size_t)total;

    // workspace layout
    uint8_t* ws = (uint8_t*)d_ws;
    unsigned* ghist  = (unsigned*)ws;                         // 1 MB
    int*      delta  = (int*)(ws + 1048576);                  // 256 B
    int2*     sel    = (int2*)(ws + 1048576 + 1024);          // 512 B
    int*      segCnt = (int*)(ws + 1048576 + 2048);           // 8 KB
    uint2*    cand   = (uint2*)(ws + 1048576 + 2048 + 8192);  // 4 MB

    // zero ghist + delta
    const int n16 = (1048576 + 1024) / 16;
    zero_ws_kernel<<<dim3((n16 + BLK - 1) / BLK), BLK, 0, stream>>>((uint4*)ws, n16);

    mfma_conv_kernel<true><<<dim3(B * 64), BLK, 0, stream>>>(x, w, sim, ghist);
    bin_select_kernel<<<dim3(B), 1024, 0, stream>>>(ghist, sel, kptr);
    write_gather_kernel<<<dim3(B * NCHUNK), BLK, 0, stream>>>(x, w, sim, ext, cand, segCnt, sel, delta);
    finalize_kernel<<<dim3(B), 1024, 0, stream>>>(sim, ext, cand, segCnt, sel, delta);
    mfma_conv_kernel<false><<<dim3(B * 64), BLK, 0, stream>>>(ext, w, recon, nullptr);
}